// Round 6
// baseline (258.853 us; speedup 1.0000x reference)
//
#include <hip/hip_runtime.h>
#include <math.h>

namespace {
constexpr int B   = 4;
constexpr int C   = 128;
constexpr int H   = 128;
constexpr int W   = 128;
constexpr int HWn = H * W;           // 16384
constexpr int NH  = 8;
}

using short8 = __attribute__((ext_vector_type(8))) short;
using f32x4  = __attribute__((ext_vector_type(4))) float;

__device__ __forceinline__ float fast_tanh(float x) {
  float e = __expf(2.f * x);
  return 1.f - 2.f / (e + 1.f);
}
__device__ __forceinline__ unsigned f2bf(float f) {  // RNE bf16 bits
  unsigned u = __float_as_uint(f);
  return (u + 0x7FFFu + ((u >> 16) & 1u)) >> 16;
}
__device__ __forceinline__ unsigned pack2bf(float a, float b) {
  return f2bf(a) | (f2bf(b) << 16);
}

// ---------------------------------------------------------------------------
// Prep: bf16 transposed weights in ws.
//   wcat_t[192][128]: rows 0..127 = Woff cols, 128..191 = Wattn cols
//   wval_t[128][128], wout_t[128][128]
// ---------------------------------------------------------------------------
__global__ __launch_bounds__(256) void prep_weights_kernel(
    const float* __restrict__ Woff, const float* __restrict__ Wattn,
    const float* __restrict__ Wval, const float* __restrict__ Wout,
    unsigned short* __restrict__ wcat_t, unsigned short* __restrict__ wval_t,
    unsigned short* __restrict__ wout_t) {
  int row = blockIdx.x * 256 + threadIdx.x;
  if (row >= 448) return;
  const float* src; int ldn; int col; unsigned short* dst;
  if (row < 192) {
    if (row < 128) { src = Woff; ldn = 128; col = row; }
    else           { src = Wattn; ldn = 64; col = row - 128; }
    dst = wcat_t + row * 128;
  } else if (row < 320) {
    src = Wval; ldn = 128; col = row - 192; dst = wval_t + (row - 192) * 128;
  } else {
    src = Wout; ldn = 128; col = row - 320; dst = wout_t + (row - 320) * 128;
  }
  for (int k0 = 0; k0 < 128; k0 += 8) {
    unsigned pk[4];
#pragma unroll
    for (int j = 0; j < 4; ++j)
      pk[j] = pack2bf(src[(k0 + 2 * j) * ldn + col],
                      src[(k0 + 2 * j + 1) * ldn + col]);
    *(uint4*)(dst + k0) = make_uint4(pk[0], pk[1], pk[2], pk[3]);
  }
}

// ---------------------------------------------------------------------------
// Kernel 1: val GEMM via MFMA 16x16x32 bf16 -> val[b][h][q][16] bf16 planes.
// (unchanged from R5 — fast there)
// ---------------------------------------------------------------------------
__global__ __launch_bounds__(256) void val_gemm_kernel(
    const float* __restrict__ nbr, const unsigned short* __restrict__ wval_t,
    const float* __restrict__ bv, unsigned short* __restrict__ val) {
  __shared__ unsigned short a_s[64 * 152];
  __shared__ unsigned short b_s[128 * 40];
  const int t    = threadIdx.x;
  const int b    = blockIdx.x >> 8;
  const int q0   = (blockIdx.x & 255) * 64;
  const int wv   = t >> 6;
  const int lane = t & 63;
  const int li   = lane & 15, quad = lane >> 4;

  const float* Ab = nbr + (size_t)b * C * HWn + q0;
#pragma unroll
  for (int it = 0; it < 4; ++it) {
    int idx = t + 256 * it;
    int kp  = idx >> 4;
    int q4  = (idx & 15) * 4;
    float4 fa = *(const float4*)(Ab + (size_t)(2 * kp) * HWn + q4);
    float4 fb = *(const float4*)(Ab + (size_t)(2 * kp + 1) * HWn + q4);
    const float* pa = &fa.x; const float* pb = &fb.x;
#pragma unroll
    for (int j = 0; j < 4; ++j)
      *(unsigned*)&a_s[(q4 + j) * 152 + 2 * kp] = pack2bf(pa[j], pb[j]);
  }

  f32x4 acc[8];
#pragma unroll
  for (int n = 0; n < 8; ++n) acc[n] = (f32x4){0.f, 0.f, 0.f, 0.f};

  for (int ck = 0; ck < 4; ++ck) {
    __syncthreads();
#pragma unroll
    for (int it = 0; it < 2; ++it) {
      int idx = t + 256 * it;
      int n = idx >> 2, seg = idx & 3;
      *(uint4*)&b_s[n * 40 + seg * 8] =
          *(const uint4*)(wval_t + n * 128 + ck * 32 + seg * 8);
    }
    __syncthreads();
    short8 af = *(const short8*)&a_s[(16 * wv + li) * 152 + ck * 32 + quad * 8];
#pragma unroll
    for (int n = 0; n < 8; ++n) {
      short8 bfr = *(const short8*)&b_s[(16 * n + li) * 40 + quad * 8];
      acc[n] = __builtin_amdgcn_mfma_f32_16x16x32_bf16(af, bfr, acc[n], 0, 0, 0);
    }
  }

  __syncthreads();
#pragma unroll
  for (int n = 0; n < 8; ++n) {
    float bias = bv[16 * n + li];
#pragma unroll
    for (int reg = 0; reg < 4; ++reg) {
      int q = 16 * wv + 4 * quad + reg;
      a_s[q * 152 + 16 * n + li] = (unsigned short)f2bf(acc[n][reg] + bias);
    }
  }
  __syncthreads();
  {
    const int qi = t & 63, r = t >> 6;
    uint4 v0 = *(const uint4*)&a_s[qi * 152 + 32 * r];
    uint4 v1 = *(const uint4*)&a_s[qi * 152 + 32 * r + 8];
    uint4 v2 = *(const uint4*)&a_s[qi * 152 + 32 * r + 16];
    uint4 v3 = *(const uint4*)&a_s[qi * 152 + 32 * r + 24];
    unsigned short* d0 = val + ((size_t)(b * NH + 2 * r) * HWn + q0 + qi) * 16;
    unsigned short* d1 = val + ((size_t)(b * NH + 2 * r + 1) * HWn + q0 + qi) * 16;
    *(uint4*)d0 = v0; *(uint4*)(d0 + 8) = v1;
    *(uint4*)d1 = v2; *(uint4*)(d1 + 8) = v3;
  }
}

// ---------------------------------------------------------------------------
// Kernel 2: fused, low-footprint. 32 q/block (16x2 px tile), 1 head/thread.
// phase1 MFMA off/attn GEMM (single bf16 A) -> LDS redistribute ->
// gather -> phase3 MFMA out-proj -> transposed coalesced stores.
// LDS 24,704 B; target VGPR ~130.
// ---------------------------------------------------------------------------
__global__ __launch_bounds__(256) void fused_kernel(
    const float* __restrict__ ext,  const float* __restrict__ flow,
    const unsigned short* __restrict__ wcat_t,
    const float* __restrict__ boff, const float* __restrict__ battn,
    const unsigned short* __restrict__ wout_t,
    const float* __restrict__ bout,
    const unsigned short* __restrict__ val, float* __restrict__ out) {
  __shared__ float smem[6176];         // 24,704 B, phase-overlaid
  const int t    = threadIdx.x;
  const int wv   = t >> 6;
  const int lane = t & 63;
  const int li   = lane & 15, quad = lane >> 4;
  const int qi   = t & 31;             // query within tile
  const int r    = t >> 5;             // head 0..7

  // XCD swizzle: 2048 blocks -> lin; 512 tiles (16x2 px) per image
  const int blk  = blockIdx.x;
  const int lin  = (blk & 7) * 256 + (blk >> 3);
  const int b    = lin >> 9;
  const int tile = lin & 511;
  const int x0   = (tile & 7) * 16;
  const int y0   = (tile >> 3) * 2;
  const int x    = x0 + (qi & 15);
  const int y    = y0 + (qi >> 4);

  // ---------------- phase 1: off/attn GEMM (32q x 192n, K=128) -------------
  unsigned short* a_su = (unsigned short*)smem;          // [32][40]
  unsigned short* bw_s = (unsigned short*)smem + 1280;   // [192][40]
  const int mt = wv & 1;               // q half
  const int nb = 6 * (wv >> 1);        // first of 6 n-tiles
  f32x4 acc[6];
#pragma unroll
  for (int n = 0; n < 6; ++n) acc[n] = (f32x4){0.f, 0.f, 0.f, 0.f};

  const float* Eb = ext + (size_t)b * C * HWn;
  for (int ck = 0; ck < 4; ++ck) {
    const int k0 = ck * 32;
    __syncthreads();
    if (t < 128) {                     // waves 0,1: stage A (bf16, [q][k])
      int kp = t >> 3, q4 = (t & 7) * 4;
      int ay = q4 >> 4, ax = q4 & 15;
      const float* srcp = Eb + (size_t)(k0 + 2 * kp) * HWn + (y0 + ay) * W + x0 + ax;
      float4 fa = *(const float4*)(srcp);
      float4 fb = *(const float4*)(srcp + HWn);
      const float* pa = &fa.x; const float* pb = &fb.x;
#pragma unroll
      for (int j = 0; j < 4; ++j)
        *(unsigned*)&a_su[(q4 + j) * 40 + 2 * kp] = pack2bf(pa[j], pb[j]);
    } else {                           // waves 2,3: stage W chunk [192][32]
      int tt = t - 128;
#pragma unroll
      for (int i = 0; i < 6; ++i) {
        int idx = tt + 128 * i;
        int n = idx >> 2, seg = idx & 3;
        *(uint4*)&bw_s[n * 40 + seg * 8] =
            *(const uint4*)(wcat_t + n * 128 + k0 + seg * 8);
      }
    }
    __syncthreads();
    short8 af = *(const short8*)&a_su[(16 * mt + li) * 40 + quad * 8];
#pragma unroll
    for (int n = 0; n < 6; ++n) {
      short8 bfr = *(const short8*)&bw_s[(16 * (nb + n) + li) * 40 + quad * 8];
      acc[n] = __builtin_amdgcn_mfma_f32_16x16x32_bf16(af, bfr, acc[n], 0, 0, 0);
    }
  }

  // redistribute: +bias, C-layout -> proj_s[q][193]
  __syncthreads();
#pragma unroll
  for (int n = 0; n < 6; ++n) {
    int col = 16 * (nb + n) + li;
    float bias = (col < 128) ? boff[col] : battn[col - 128];
#pragma unroll
    for (int reg = 0; reg < 4; ++reg) {
      int q = 16 * mt + 4 * quad + reg;
      smem[q * 193 + col] = acc[n][reg] + bias;
    }
  }
  __syncthreads();

  // ---------------- phase 2: epilogues + bilinear gather (1 head) ----------
  float offa[16];
  float atta[8];
#pragma unroll
  for (int j = 0; j < 16; ++j)
    offa[j] = 10.f * fast_tanh(smem[qi * 193 + 16 * r + j]);
#pragma unroll
  for (int j = 0; j < 8; ++j) atta[j] = smem[qi * 193 + 128 + 8 * r + j];
  {
    float m = atta[0];
#pragma unroll
    for (int p = 1; p < 8; ++p) m = fmaxf(m, atta[p]);
    float s = 0.f;
#pragma unroll
    for (int p = 0; p < 8; ++p) { float ev = __expf(atta[p] - m); atta[p] = ev; s += ev; }
    float inv = 1.f / s;
#pragma unroll
    for (int p = 0; p < 8; ++p) atta[p] *= inv;
  }
  __syncthreads();                     // proj_s dead; smem reusable

  const float xb = (float)x + flow[(size_t)b * 2 * HWn + y * W + x];
  const float yb = (float)y + flow[((size_t)b * 2 + 1) * HWn + y * W + x];

  float agg[16];
#pragma unroll
  for (int j = 0; j < 16; ++j) agg[j] = 0.f;
  const unsigned short* valh = val + (size_t)(b * NH + r) * HWn * 16;

#pragma unroll
  for (int p = 0; p < 8; ++p) {
    float sx = xb + offa[2 * p];
    float sy = yb + offa[2 * p + 1];
    float x0f = floorf(sx), y0f = floorf(sy);
    float wx = sx - x0f, wy = sy - y0f;
    int ix0 = (int)x0f, iy0 = (int)y0f;
    int ix1 = ix0 + 1,  iy1 = iy0 + 1;
    float aw  = atta[p];
    float w00 = aw * (1.f - wx) * (1.f - wy);
    float w10 = aw * wx * (1.f - wy);
    float w01 = aw * (1.f - wx) * wy;
    float w11 = aw * wx * wy;
    if ((unsigned)ix0 >= (unsigned)W) { w00 = 0.f; w01 = 0.f; }
    if ((unsigned)ix1 >= (unsigned)W) { w10 = 0.f; w11 = 0.f; }
    if ((unsigned)iy0 >= (unsigned)H) { w00 = 0.f; w10 = 0.f; }
    if ((unsigned)iy1 >= (unsigned)H) { w01 = 0.f; w11 = 0.f; }
    int x0c = min(max(ix0, 0), W - 1);
    int x1c = min(max(ix1, 0), W - 1);
    int y0c = min(max(iy0, 0), H - 1);
    int y1c = min(max(iy1, 0), H - 1);
    const unsigned short* c00 = valh + (size_t)(y0c * W + x0c) * 16;
    const unsigned short* c10 = valh + (size_t)(y0c * W + x1c) * 16;
    const unsigned short* c01 = valh + (size_t)(y1c * W + x0c) * 16;
    const unsigned short* c11 = valh + (size_t)(y1c * W + x1c) * 16;
#pragma unroll
    for (int cn = 0; cn < 4; ++cn) {
      const unsigned short* cp = (cn == 0) ? c00 : (cn == 1) ? c10
                                : (cn == 2) ? c01 : c11;
      float wgt = (cn == 0) ? w00 : (cn == 1) ? w10 : (cn == 2) ? w01 : w11;
      uint4 ga = ((const uint4*)cp)[0];
      uint4 gb = ((const uint4*)cp)[1];
      unsigned gs[8] = {ga.x, ga.y, ga.z, ga.w, gb.x, gb.y, gb.z, gb.w};
#pragma unroll
      for (int i = 0; i < 8; ++i) {
        float lo = __uint_as_float(gs[i] << 16);
        float hi = __uint_as_float(gs[i] & 0xFFFF0000u);
        agg[2 * i]     += wgt * lo;
        agg[2 * i + 1] += wgt * hi;
      }
    }
  }

  // ---------------- phase 3: out projection via MFMA (32q x 128) -----------
  unsigned short* ag   = (unsigned short*)smem;          // [32][136]
  unsigned short* w2_s = (unsigned short*)smem + 2 * 2176; // [128][40]
  {
    unsigned pk[8];
#pragma unroll
    for (int i = 0; i < 8; ++i) pk[i] = pack2bf(agg[2 * i], agg[2 * i + 1]);
    uint4* dst = (uint4*)&ag[qi * 136 + 16 * r];
    dst[0] = make_uint4(pk[0], pk[1], pk[2], pk[3]);
    dst[1] = make_uint4(pk[4], pk[5], pk[6], pk[7]);
  }

  const int nb2 = 4 * (wv >> 1);
  f32x4 acc2[4];
#pragma unroll
  for (int n = 0; n < 4; ++n) acc2[n] = (f32x4){0.f, 0.f, 0.f, 0.f};

  for (int ck = 0; ck < 4; ++ck) {
    __syncthreads();                   // first iter: fences ag writes
#pragma unroll
    for (int i = 0; i < 2; ++i) {
      int idx = t + 256 * i;
      int n = idx >> 2, seg = idx & 3;
      *(uint4*)&w2_s[n * 40 + seg * 8] =
          *(const uint4*)(wout_t + n * 128 + ck * 32 + seg * 8);
    }
    __syncthreads();
    short8 af2 = *(const short8*)&ag[(16 * mt + li) * 136 + ck * 32 + quad * 8];
#pragma unroll
    for (int n = 0; n < 4; ++n) {
      short8 bfr = *(const short8*)&w2_s[(16 * (nb2 + n) + li) * 40 + quad * 8];
      acc2[n] = __builtin_amdgcn_mfma_f32_16x16x32_bf16(af2, bfr, acc2[n], 0, 0, 0);
    }
  }

  // ---------------- phase 4: +bias, transpose via LDS, coalesced stores ----
  __syncthreads();                     // ag/w2 dead
#pragma unroll
  for (int n = 0; n < 4; ++n) {
    int c = 16 * (nb2 + n) + li;
    float bias = bout[c];
#pragma unroll
    for (int reg = 0; reg < 4; ++reg)
      smem[c * 37 + 16 * mt + 4 * quad + reg] = acc2[n][reg] + bias;
  }
  __syncthreads();
  {
    const int c  = t >> 1;
    const int yy = t & 1;
    float* orow = out + (size_t)b * C * HWn + (size_t)c * HWn + (y0 + yy) * W + x0;
#pragma unroll
    for (int s = 0; s < 4; ++s) {
      float4 v;
      v.x = smem[c * 37 + yy * 16 + 4 * s + 0];
      v.y = smem[c * 37 + yy * 16 + 4 * s + 1];
      v.z = smem[c * 37 + yy * 16 + 4 * s + 2];
      v.w = smem[c * 37 + yy * 16 + 4 * s + 3];
      *(float4*)(orow + 4 * s) = v;
    }
  }
}

extern "C" void kernel_launch(void* const* d_in, const int* in_sizes, int n_in,
                              void* d_out, int out_size, void* d_ws, size_t ws_size,
                              hipStream_t stream) {
  const float* nbr   = (const float*)d_in[0];
  const float* extf  = (const float*)d_in[1];
  const float* flow  = (const float*)d_in[2];
  const float* Woff  = (const float*)d_in[3];
  const float* boff  = (const float*)d_in[4];
  const float* Wattn = (const float*)d_in[5];
  const float* battn = (const float*)d_in[6];
  const float* Wval  = (const float*)d_in[7];
  const float* bval  = (const float*)d_in[8];
  const float* Wout  = (const float*)d_in[9];
  const float* bout  = (const float*)d_in[10];
  float* outp = (float*)d_out;

  unsigned short* val    = (unsigned short*)d_ws;      // 16.78 MB
  unsigned short* wcat_t = val + (size_t)B * NH * HWn * 16;
  unsigned short* wval_t = wcat_t + 192 * 128;
  unsigned short* wout_t = wval_t + 128 * 128;         // total ~16.9 MB

  prep_weights_kernel<<<dim3(2), dim3(256), 0, stream>>>(
      Woff, Wattn, Wval, Wout, wcat_t, wval_t, wout_t);
  val_gemm_kernel<<<dim3(1024), dim3(256), 0, stream>>>(
      nbr, wval_t, bval, val);
  fused_kernel<<<dim3(2048), dim3(256), 0, stream>>>(
      extf, flow, wcat_t, boff, battn, wout_t, bout, val, outp);
}

// Round 7
// 231.761 us; speedup vs baseline: 1.1169x; 1.1169x over previous
//
#include <hip/hip_runtime.h>
#include <math.h>

namespace {
constexpr int B   = 4;
constexpr int C   = 128;
constexpr int H   = 128;
constexpr int W   = 128;
constexpr int HWn = H * W;           // 16384
constexpr int NH  = 8;
constexpr int KC  = 16;              // out-proj k-chunk (K2)
}

using short8 = __attribute__((ext_vector_type(8))) short;
using f32x4  = __attribute__((ext_vector_type(4))) float;

__device__ __forceinline__ float fast_tanh(float x) {
  float e = __expf(2.f * x);
  return 1.f - 2.f / (e + 1.f);
}
__device__ __forceinline__ unsigned f2bf(float f) {  // RNE bf16 bits
  unsigned u = __float_as_uint(f);
  return (u + 0x7FFFu + ((u >> 16) & 1u)) >> 16;
}
__device__ __forceinline__ unsigned pack2bf(float a, float b) {
  return f2bf(a) | (f2bf(b) << 16);
}

// ---------------------------------------------------------------------------
// Prep: bf16 transposed weights in ws.
//   wcat_t[192][128]: rows 0..127 = Woff cols, 128..191 = Wattn cols
//   wval_t[128][128]
// ---------------------------------------------------------------------------
__global__ __launch_bounds__(256) void prep_weights_kernel(
    const float* __restrict__ Woff, const float* __restrict__ Wattn,
    const float* __restrict__ Wval,
    unsigned short* __restrict__ wcat_t, unsigned short* __restrict__ wval_t) {
  int row = blockIdx.x * 256 + threadIdx.x;
  if (row >= 320) return;
  const float* src; int ldn; int col; unsigned short* dst;
  if (row < 192) {
    if (row < 128) { src = Woff; ldn = 128; col = row; }
    else           { src = Wattn; ldn = 64; col = row - 128; }
    dst = wcat_t + row * 128;
  } else {
    src = Wval; ldn = 128; col = row - 192; dst = wval_t + (row - 192) * 128;
  }
  for (int k0 = 0; k0 < 128; k0 += 8) {
    unsigned pk[4];
#pragma unroll
    for (int j = 0; j < 4; ++j)
      pk[j] = pack2bf(src[(k0 + 2 * j) * ldn + col],
                      src[(k0 + 2 * j + 1) * ldn + col]);
    *(uint4*)(dst + k0) = make_uint4(pk[0], pk[1], pk[2], pk[3]);
  }
}

// ---------------------------------------------------------------------------
// K1: both input GEMMs via MFMA 16x16x32 bf16. 64-q strips.
//   grp0 (blocks 0..1023):    val[b][h][q][16] bf16  = nbr^T @ Wval + bval
//   grp1 (blocks 1024..2047): proj[b][q][0:192] fp32 = ext^T @ [Woff|Wattn]
//                             (raw logits + bias; epilogues applied in K2)
// ---------------------------------------------------------------------------
__global__ __launch_bounds__(256) void gemm_kernel(
    const float* __restrict__ nbr, const float* __restrict__ ext,
    const unsigned short* __restrict__ wval_t,
    const float* __restrict__ bv,
    const unsigned short* __restrict__ wcat_t,
    const float* __restrict__ boff, const float* __restrict__ battn,
    unsigned short* __restrict__ val, float* __restrict__ proj) {
  __shared__ unsigned short a_s[64 * 152];   // 19456 B; A bf16 [q][k]
  __shared__ unsigned short b_s[192 * 40];   // 15360 B; B chunk [n][32k]
  const int t    = threadIdx.x;
  const int grp  = blockIdx.x >> 10;
  const int id   = blockIdx.x & 1023;
  const int b    = id >> 8;
  const int q0   = (id & 255) * 64;
  const int wv   = t >> 6;
  const int lane = t & 63;
  const int li   = lane & 15, quad = lane >> 4;

  // stage A (all 128 k): src[k][q] fp32 -> a_s[q][k] bf16, k-pairs packed
  const float* Ab = (grp ? ext : nbr) + (size_t)b * C * HWn + q0;
#pragma unroll
  for (int it = 0; it < 4; ++it) {
    int idx = t + 256 * it;
    int kp  = idx >> 4;
    int q4  = (idx & 15) * 4;
    float4 fa = *(const float4*)(Ab + (size_t)(2 * kp) * HWn + q4);
    float4 fb = *(const float4*)(Ab + (size_t)(2 * kp + 1) * HWn + q4);
    const float* pa = &fa.x; const float* pb = &fb.x;
#pragma unroll
    for (int j = 0; j < 4; ++j)
      *(unsigned*)&a_s[(q4 + j) * 152 + 2 * kp] = pack2bf(pa[j], pb[j]);
  }

  if (grp == 0) {
    // ------------------------- val GEMM: 64q x 128c -----------------------
    f32x4 acc[8];
#pragma unroll
    for (int n = 0; n < 8; ++n) acc[n] = (f32x4){0.f, 0.f, 0.f, 0.f};

    for (int ck = 0; ck < 4; ++ck) {
      __syncthreads();
#pragma unroll
      for (int it = 0; it < 2; ++it) {
        int idx = t + 256 * it;
        int n = idx >> 2, seg = idx & 3;
        *(uint4*)&b_s[n * 40 + seg * 8] =
            *(const uint4*)(wval_t + n * 128 + ck * 32 + seg * 8);
      }
      __syncthreads();
      short8 af = *(const short8*)&a_s[(16 * wv + li) * 152 + ck * 32 + quad * 8];
#pragma unroll
      for (int n = 0; n < 8; ++n) {
        short8 bfr = *(const short8*)&b_s[(16 * n + li) * 40 + quad * 8];
        acc[n] = __builtin_amdgcn_mfma_f32_16x16x32_bf16(af, bfr, acc[n], 0, 0, 0);
      }
    }

    // epilogue: +bias, C-layout -> a_s[q][c] bf16, coalesced head-plane store
    __syncthreads();
#pragma unroll
    for (int n = 0; n < 8; ++n) {
      float bias = bv[16 * n + li];
#pragma unroll
      for (int reg = 0; reg < 4; ++reg) {
        int q = 16 * wv + 4 * quad + reg;
        a_s[q * 152 + 16 * n + li] = (unsigned short)f2bf(acc[n][reg] + bias);
      }
    }
    __syncthreads();
    {
      const int qi = t & 63, r = t >> 6;
      uint4 v0 = *(const uint4*)&a_s[qi * 152 + 32 * r];
      uint4 v1 = *(const uint4*)&a_s[qi * 152 + 32 * r + 8];
      uint4 v2 = *(const uint4*)&a_s[qi * 152 + 32 * r + 16];
      uint4 v3 = *(const uint4*)&a_s[qi * 152 + 32 * r + 24];
      unsigned short* d0 = val + ((size_t)(b * NH + 2 * r) * HWn + q0 + qi) * 16;
      unsigned short* d1 = val + ((size_t)(b * NH + 2 * r + 1) * HWn + q0 + qi) * 16;
      *(uint4*)d0 = v0; *(uint4*)(d0 + 8) = v1;
      *(uint4*)d1 = v2; *(uint4*)(d1 + 8) = v3;
    }
  } else {
    // --------------------- off/attn logits GEMM: 64q x 192 ----------------
    f32x4 acc[12];
#pragma unroll
    for (int n = 0; n < 12; ++n) acc[n] = (f32x4){0.f, 0.f, 0.f, 0.f};

    for (int ck = 0; ck < 4; ++ck) {
      __syncthreads();
#pragma unroll
      for (int it = 0; it < 3; ++it) {
        int idx = t + 256 * it;
        int n = idx >> 2, seg = idx & 3;
        *(uint4*)&b_s[n * 40 + seg * 8] =
            *(const uint4*)(wcat_t + n * 128 + ck * 32 + seg * 8);
      }
      __syncthreads();
      short8 af = *(const short8*)&a_s[(16 * wv + li) * 152 + ck * 32 + quad * 8];
#pragma unroll
      for (int n = 0; n < 12; ++n) {
        short8 bfr = *(const short8*)&b_s[(16 * n + li) * 40 + quad * 8];
        acc[n] = __builtin_amdgcn_mfma_f32_16x16x32_bf16(af, bfr, acc[n], 0, 0, 0);
      }
    }

    // +bias, store raw logits from C-layout (16-lane 64B segments)
#pragma unroll
    for (int n = 0; n < 12; ++n) {
      int col = 16 * n + li;
      float bias = (col < 128) ? boff[col] : battn[col - 128];
#pragma unroll
      for (int reg = 0; reg < 4; ++reg) {
        int q = 16 * wv + 4 * quad + reg;
        proj[(size_t)(b * HWn + q0 + q) * 192 + col] = acc[n][reg] + bias;
      }
    }
  }
}

// ---------------------------------------------------------------------------
// K2: gather + out projection (R4 structure, GEMV removed).
// 16x4 px tiles, XCD swizzle, thread = (qi, r) -> heads 2r, 2r+1.
// Reads raw logits from proj, applies tanh/softmax in-thread.
// ---------------------------------------------------------------------------
__global__ __launch_bounds__(256) void gather_out_kernel(
    const float* __restrict__ flow, const float* __restrict__ proj,
    const unsigned short* __restrict__ val,
    const float* __restrict__ Wout, const float* __restrict__ bout,
    float* __restrict__ out) {
  __shared__ float agg_s[C * 64];      // 32 KB, [c][qi]
  __shared__ float w_s[KC * 128];      // 8 KB
  const int t  = threadIdx.x;
  const int qi = t & 63;
  const int r  = t >> 6;

  const int blk  = blockIdx.x;
  const int lin  = (blk & 7) * 128 + (blk >> 3);
  const int b    = lin >> 8;
  const int tile = lin & 255;
  const int x0   = (tile & 7) * 16;
  const int y0   = (tile >> 3) * 4;
  const int x    = x0 + (qi & 15);
  const int y    = y0 + (qi >> 4);

  // ---- logits -> offsets / attention (in-thread epilogues)
  const float* pp = proj + (size_t)(b * HWn + y * W + x) * 192;
  float offa[32];
  float atta[16];
#pragma unroll
  for (int j4 = 0; j4 < 8; ++j4) {
    float4 v = *(const float4*)(pp + 32 * r + 4 * j4);
    offa[4 * j4 + 0] = 10.f * fast_tanh(v.x);
    offa[4 * j4 + 1] = 10.f * fast_tanh(v.y);
    offa[4 * j4 + 2] = 10.f * fast_tanh(v.z);
    offa[4 * j4 + 3] = 10.f * fast_tanh(v.w);
  }
#pragma unroll
  for (int j4 = 0; j4 < 4; ++j4) {
    float4 v = *(const float4*)(pp + 128 + 16 * r + 4 * j4);
    atta[4 * j4 + 0] = v.x; atta[4 * j4 + 1] = v.y;
    atta[4 * j4 + 2] = v.z; atta[4 * j4 + 3] = v.w;
  }
#pragma unroll
  for (int u = 0; u < 2; ++u) {
    float* a = atta + 8 * u;
    float m = a[0];
#pragma unroll
    for (int p = 1; p < 8; ++p) m = fmaxf(m, a[p]);
    float s = 0.f;
#pragma unroll
    for (int p = 0; p < 8; ++p) { float ev = __expf(a[p] - m); a[p] = ev; s += ev; }
    float inv = 1.f / s;
#pragma unroll
    for (int p = 0; p < 8; ++p) a[p] *= inv;
  }

  // ---- bilinear gather from bf16 head planes
  const float xb = (float)x + flow[(size_t)b * 2 * HWn + y * W + x];
  const float yb = (float)y + flow[((size_t)b * 2 + 1) * HWn + y * W + x];

  float agg[32];
#pragma unroll
  for (int j = 0; j < 32; ++j) agg[j] = 0.f;
  const unsigned short* valb = val + (size_t)b * NH * HWn * 16;

#pragma unroll
  for (int u = 0; u < 2; ++u) {
    const unsigned short* valh = valb + (size_t)(2 * r + u) * HWn * 16;
    float* aggh = agg + 16 * u;
#pragma unroll
    for (int p = 0; p < 8; ++p) {
      float sx = xb + offa[u * 16 + 2 * p];
      float sy = yb + offa[u * 16 + 2 * p + 1];
      float x0f = floorf(sx), y0f = floorf(sy);
      float wx = sx - x0f, wy = sy - y0f;
      int ix0 = (int)x0f, iy0 = (int)y0f;
      int ix1 = ix0 + 1,  iy1 = iy0 + 1;
      float aw  = atta[u * 8 + p];
      float w00 = aw * (1.f - wx) * (1.f - wy);
      float w10 = aw * wx * (1.f - wy);
      float w01 = aw * (1.f - wx) * wy;
      float w11 = aw * wx * wy;
      if ((unsigned)ix0 >= (unsigned)W) { w00 = 0.f; w01 = 0.f; }
      if ((unsigned)ix1 >= (unsigned)W) { w10 = 0.f; w11 = 0.f; }
      if ((unsigned)iy0 >= (unsigned)H) { w00 = 0.f; w10 = 0.f; }
      if ((unsigned)iy1 >= (unsigned)H) { w01 = 0.f; w11 = 0.f; }
      int x0c = min(max(ix0, 0), W - 1);
      int x1c = min(max(ix1, 0), W - 1);
      int y0c = min(max(iy0, 0), H - 1);
      int y1c = min(max(iy1, 0), H - 1);
      const unsigned short* c00 = valh + (size_t)(y0c * W + x0c) * 16;
      const unsigned short* c10 = valh + (size_t)(y0c * W + x1c) * 16;
      const unsigned short* c01 = valh + (size_t)(y1c * W + x0c) * 16;
      const unsigned short* c11 = valh + (size_t)(y1c * W + x1c) * 16;
#pragma unroll
      for (int cn = 0; cn < 4; ++cn) {
        const unsigned short* cp = (cn == 0) ? c00 : (cn == 1) ? c10
                                  : (cn == 2) ? c01 : c11;
        float wgt = (cn == 0) ? w00 : (cn == 1) ? w10 : (cn == 2) ? w01 : w11;
        uint4 ga = ((const uint4*)cp)[0];
        uint4 gb = ((const uint4*)cp)[1];
        unsigned gs[8] = {ga.x, ga.y, ga.z, ga.w, gb.x, gb.y, gb.z, gb.w};
#pragma unroll
        for (int i = 0; i < 8; ++i) {
          float lo = __uint_as_float(gs[i] << 16);
          float hi = __uint_as_float(gs[i] & 0xFFFF0000u);
          aggh[2 * i]     += wgt * lo;
          aggh[2 * i + 1] += wgt * hi;
        }
      }
    }
  }

  // ---- agg -> LDS [c][qi] (2-way aliasing only), VALU out-projection
#pragma unroll
  for (int j = 0; j < 32; ++j) agg_s[(32 * r + j) * 64 + qi] = agg[j];

  float acc[32];
#pragma unroll
  for (int j = 0; j < 32; ++j) acc[j] = bout[32 * r + j];

  for (int ck = 0; ck < C / KC; ++ck) {
    const int k0 = ck * KC;
#pragma unroll
    for (int i = 0; i < 2; ++i) {
      int idx = t + 256 * i;
      int k = idx >> 5, col = (idx & 31) * 4;
      *(float4*)&w_s[k * 128 + col] =
          *(const float4*)(Wout + (size_t)(k0 + k) * 128 + col);
    }
    __syncthreads();                   // first iter also fences agg_s writes
#pragma unroll
    for (int k = 0; k < KC; ++k) {
      float a = agg_s[(k0 + k) * 64 + qi];
      const float4* wp = (const float4*)&w_s[k * 128 + 32 * r];
#pragma unroll
      for (int j4 = 0; j4 < 8; ++j4) {
        float4 w = wp[j4];
        acc[4 * j4 + 0] += a * w.x; acc[4 * j4 + 1] += a * w.y;
        acc[4 * j4 + 2] += a * w.z; acc[4 * j4 + 3] += a * w.w;
      }
    }
    __syncthreads();
  }

  // stores: per channel, lanes cover the 16x4 tile (4 x 64B row segments)
  float* ob = out + (size_t)b * C * HWn + y * W + x;
#pragma unroll
  for (int j = 0; j < 32; ++j)
    ob[(size_t)(32 * r + j) * HWn] = acc[j];
}

extern "C" void kernel_launch(void* const* d_in, const int* in_sizes, int n_in,
                              void* d_out, int out_size, void* d_ws, size_t ws_size,
                              hipStream_t stream) {
  const float* nbr   = (const float*)d_in[0];
  const float* extf  = (const float*)d_in[1];
  const float* flow  = (const float*)d_in[2];
  const float* Woff  = (const float*)d_in[3];
  const float* boff  = (const float*)d_in[4];
  const float* Wattn = (const float*)d_in[5];
  const float* battn = (const float*)d_in[6];
  const float* Wval  = (const float*)d_in[7];
  const float* bval  = (const float*)d_in[8];
  const float* Wout  = (const float*)d_in[9];
  const float* bout  = (const float*)d_in[10];
  float* outp = (float*)d_out;

  // ws layout: val bf16 16.78 MB | wcat_t 48 KB | wval_t 32 KB | proj 50.3 MB
  // total ~67.2 MB (R3 proved ws >= 84 MB).
  unsigned short* val    = (unsigned short*)d_ws;
  unsigned short* wcat_t = val + (size_t)B * NH * HWn * 16;
  unsigned short* wval_t = wcat_t + 192 * 128;
  float*          proj   = (float*)(wval_t + 128 * 128);

  prep_weights_kernel<<<dim3(2), dim3(256), 0, stream>>>(
      Woff, Wattn, Wval, wcat_t, wval_t);
  gemm_kernel<<<dim3(2048), dim3(256), 0, stream>>>(
      nbr, extf, wval_t, bval, wcat_t, boff, battn, val, proj);
  gather_out_kernel<<<dim3(1024), dim3(256), 0, stream>>>(
      flow, proj, val, Wout, bout, outp);
}